// Round 16
// baseline (226.503 us; speedup 1.0000x reference)
//
#include <hip/hip_runtime.h>
#include <cstdint>
#include <cstddef>

#define NNODES 100000
#define NEDGES 1600000
#define NWIN 100
#define WIN_NODES 1000
#define WCAP 17408
#define WSTR 16

#define GM_ROWS 64
#define GEMM_BLOCKS ((NNODES + GM_ROWS - 1) / GM_ROWS)   // 1563
#define BUCKET_BLOCKS 512
#define BCHUNK ((NEDGES + BUCKET_BLOCKS - 1) / BUCKET_BLOCKS)  // 3125
#define MEGA_BLOCKS (GEMM_BLOCKS + BUCKET_BLOCKS)        // 2075

typedef __attribute__((ext_vector_type(8))) short bf16x8;
typedef __attribute__((ext_vector_type(4))) float f32x4;

__device__ inline unsigned short f2bf(float f) {
    union { float f; unsigned u; } v; v.f = f;
    unsigned r = v.u + 0x7FFFu + ((v.u >> 16) & 1u);   // RNE
    return (unsigned short)(r >> 16);
}
__device__ inline void bfpair(unsigned u, float& lo, float& hi) {
    union { unsigned x; float f; } a, b;
    a.x = u << 16; b.x = u & 0xffff0000u;
    lo = a.f; hi = b.f;
}

#define GLOAD_LDS16(gp, lp)                                                        \
    __builtin_amdgcn_global_load_lds(                                              \
        (__attribute__((address_space(1))) const void*)(gp),                       \
        (__attribute__((address_space(3))) void*)(lp), 16, 0, 0)

// ---------------- W1 convert+transpose (+ wcur zero) ----------------

__global__ __launch_bounds__(256) void convW(const float* __restrict__ W,
                                             unsigned short* __restrict__ Wt,
                                             int* __restrict__ wcur) {
    if (blockIdx.x == 0 && threadIdx.x < NWIN) wcur[threadIdx.x * WSTR] = 0;
    int i = blockIdx.x * 256 + threadIdx.x;
    if (i < 512 * 64) {
        int k = i >> 6, n = i & 63;
        Wt[n * 512 + k] = f2bf(W[i]);
    }
}

// ---------------- MEGA kernel: DMA-staged GEMM role + edge-bucketing role ----------------
// GEMM role: A staged f32 via global_load_lds (direct DMA, no VGPR round-trip),
// wave-private 16-row slices (no barriers), double-buffered with counted
// vmcnt(4). Swizzle (16B-unit ^= row&15) applied on the GLOBAL source address
// (m173 pattern) and undone at ds_read -> conflict-free. f32->bf16 at
// fragment-read via v_cvt_pk_bf16_f32. B direct from L2-hot bf16 Wt.

__global__ __launch_bounds__(256) void mega_gemm_bucket(
        const float* __restrict__ A,            // [M,512] x
        const unsigned short* __restrict__ Wt,  // [64][512] bf16
        unsigned short* __restrict__ Hs,        // [M,64] bf16 UNSCALED out
        const int* __restrict__ src, const int* __restrict__ dst,
        unsigned* __restrict__ stage,
        int* __restrict__ wcur, int M, int E) {
    __shared__ __align__(16) char smem[32768];  // 2 bufs x 4 waves x 16 rows x 64 f32

    long long b = blockIdx.x;
    int g0 = (int)((b * GEMM_BLOCKS) / MEGA_BLOCKS);
    int g1 = (int)(((b + 1) * GEMM_BLOCKS) / MEGA_BLOCKS);

    if (g1 > g0) {
        // ---------------- GEMM role ----------------
        const int tid = threadIdx.x;
        const int wv = tid >> 6;
        const int lane = tid & 63;
        const int lm = lane & 15;
        const int lk8 = (lane >> 4);            // k-group 0..3 (8 f32 each)
        const int bm = g0 * GM_ROWS;
        const int wbase = bm + wv * 16;         // wave's 16-row base

        f32x4 acc[4];
#pragma unroll
        for (int j = 0; j < 4; j++) acc[j] = (f32x4){0.f, 0.f, 0.f, 0.f};

        // staging geometry (per issue i): lane covers row_local = 4i+(l>>4),
        // 16B unit (l&15), global unit pre-swizzled by ^row_local.
        const int st_rl = lane >> 4;            // 0..3
        const int st_u = lane & 15;

        auto ISSUE_A = [&](int k0, int bsel) {
#pragma unroll
            for (int i = 0; i < 4; i++) {
                int rl = 4 * i + st_rl;
                int grow = wbase + rl;
                grow = min(grow, M - 1);
                int su = st_u ^ rl;                       // swizzled 16B unit
                const float* gp = A + (size_t)grow * 512 + k0 + su * 4;
                char* lp = smem + bsel * 16384 + wv * 4096 + i * 1024;
                GLOAD_LDS16(gp, lp);
            }
        };

        ISSUE_A(0, 0);
        for (int t = 0; t < 8; t++) {
            const int k0 = t * 64;
            const int bsel = t & 1;

            // B fragments for this tile (direct from L2-hot Wt)
            bf16x8 bb[4][2];
#pragma unroll
            for (int cf = 0; cf < 4; cf++)
#pragma unroll
                for (int kf = 0; kf < 2; kf++)
                    bb[cf][kf] = *(const bf16x8*)&Wt[(size_t)(cf * 16 + lm) * 512
                                                     + k0 + kf * 32 + lk8 * 8];

            if (t < 7) ISSUE_A(k0 + 64, bsel ^ 1);

            if (t < 7) { asm volatile("s_waitcnt vmcnt(4)" ::: "memory"); }
            else       { asm volatile("s_waitcnt vmcnt(0)" ::: "memory"); }
            __builtin_amdgcn_sched_barrier(0);

            // A fragments: two 16B LDS reads (swizzle-corrected) + cvt_pk
            bf16x8 af[2];
#pragma unroll
            for (int kf = 0; kf < 2; kf++) {
                int u0 = kf * 8 + (lk8 << 1);
                const char* base = smem + bsel * 16384 + wv * 4096 + lm * 256;
                float4 lo = *(const float4*)(base + (((u0)     ^ lm) << 4));
                float4 hi = *(const float4*)(base + (((u0 + 1) ^ lm) << 4));
                unsigned c[4];
                asm("v_cvt_pk_bf16_f32 %0, %1, %2" : "=v"(c[0]) : "v"(lo.x), "v"(lo.y));
                asm("v_cvt_pk_bf16_f32 %0, %1, %2" : "=v"(c[1]) : "v"(lo.z), "v"(lo.w));
                asm("v_cvt_pk_bf16_f32 %0, %1, %2" : "=v"(c[2]) : "v"(hi.x), "v"(hi.y));
                asm("v_cvt_pk_bf16_f32 %0, %1, %2" : "=v"(c[3]) : "v"(hi.z), "v"(hi.w));
                af[kf] = *(bf16x8*)c;
            }

            __builtin_amdgcn_s_setprio(1);
#pragma unroll
            for (int kf = 0; kf < 2; kf++)
#pragma unroll
                for (int cf = 0; cf < 4; cf++)
                    acc[cf] = __builtin_amdgcn_mfma_f32_16x16x32_bf16(
                        af[kf], bb[cf][kf], acc[cf], 0, 0, 0);
            __builtin_amdgcn_s_setprio(0);
        }

        // epilogue: D col = lane&15, row = (lane>>4)*4 + j
#pragma unroll
        for (int j = 0; j < 4; j++) {
            int row = wbase + (lane >> 4) * 4 + j;
            if (row < M) {
#pragma unroll
                for (int cf = 0; cf < 4; cf++)
                    Hs[(size_t)row * 64 + cf * 16 + lm] = f2bf(acc[cf][j]);
            }
        }
    } else {
        // ---------------- bucket role ----------------
        int bi = (int)(b - g0);
        int* cnt  = (int*)smem;
        int* lcur = cnt + NWIN;
        const int tid = threadIdx.x;
        int e0 = bi * BCHUNK;
        int e1 = e0 + BCHUNK; if (e1 > E) e1 = E;

        for (int i = tid; i < NWIN; i += 256) cnt[i] = 0;
        __syncthreads();
        for (int e = e0 + tid; e < e1; e += 256)
            atomicAdd(&cnt[dst[e] / WIN_NODES], 1);
        __syncthreads();
        for (int i = tid; i < NWIN; i += 256)
            lcur[i] = atomicAdd(&wcur[i * WSTR], cnt[i]);
        __syncthreads();
        for (int e = e0 + tid; e < e1; e += 256) {
            int d = dst[e], s = src[e];
            int w = d / WIN_NODES;
            int pos = atomicAdd(&lcur[w], 1);
            if (pos < WCAP)
                stage[(size_t)w * WCAP + pos] =
                    ((unsigned)(d - w * WIN_NODES) << 17) | (unsigned)s;
        }
    }
}

// ---------------- csr_window: hist + scan + dinv + rowstart + fill ----------------

__global__ __launch_bounds__(256) void csr_window(
        const unsigned* __restrict__ stage,
        const int* __restrict__ wcur,
        int* __restrict__ rowstart,   // [NNODES+1]
        float* __restrict__ dinv,     // [NNODES]
        int* __restrict__ csr) {
    __shared__ int cnt[WIN_NODES];
    __shared__ int red[256];
    const int w = blockIdx.x;
    const int t = threadIdx.x;
    const int wb = w * WIN_NODES;
    const size_t sb = (size_t)w * WCAP;

    int v = (t < w) ? min(wcur[t * WSTR], WCAP) : 0;
    red[t] = v;
    __syncthreads();
#pragma unroll
    for (int off = 128; off > 0; off >>= 1) {
        if (t < off) red[t] += red[t + off];
        __syncthreads();
    }
    int woff = red[0];
    int n_w = min(wcur[w * WSTR], WCAP);
    __syncthreads();

    for (int i = t; i < WIN_NODES; i += 256) cnt[i] = 0;
    __syncthreads();
    for (int i = t; i < n_w; i += 256)
        atomicAdd(&cnt[stage[sb + i] >> 17], 1);
    __syncthreads();

    int c0 = 0, c1 = 0, c2 = 0, c3 = 0, psum = 0;
    if (t < 250) {
        c0 = cnt[4 * t]; c1 = cnt[4 * t + 1]; c2 = cnt[4 * t + 2]; c3 = cnt[4 * t + 3];
        psum = c0 + c1 + c2 + c3;
    }
    red[t] = psum;
    __syncthreads();
#pragma unroll
    for (int off = 1; off < 256; off <<= 1) {
        int tv = (t >= off) ? red[t - off] : 0;
        __syncthreads();
        red[t] += tv;
        __syncthreads();
    }
    int excl = red[t] - psum;
    if (t < 250) {
        int running = woff + excl;
        int idx = 4 * t;
        rowstart[wb + idx] = running; dinv[wb + idx] = rsqrtf((float)c0 + 1.f);
        cnt[idx] = running; running += c0;
        rowstart[wb + idx + 1] = running; dinv[wb + idx + 1] = rsqrtf((float)c1 + 1.f);
        cnt[idx + 1] = running; running += c1;
        rowstart[wb + idx + 2] = running; dinv[wb + idx + 2] = rsqrtf((float)c2 + 1.f);
        cnt[idx + 2] = running; running += c2;
        rowstart[wb + idx + 3] = running; dinv[wb + idx + 3] = rsqrtf((float)c3 + 1.f);
        cnt[idx + 3] = running;
    }
    if (w == NWIN - 1 && t == 0) rowstart[NNODES] = woff + n_w;
    __syncthreads();

    for (int i = t; i < n_w; i += 256) {
        unsigned p = stage[sb + i];
        int dl = (int)(p >> 17);
        int s  = (int)(p & 0x1FFFFu);
        int pos = atomicAdd(&cnt[dl], 1);
        csr[pos] = s;
    }
}

// ---------------- gather64 + fused 64->16 transform (per-edge dinv) ----------------

__global__ __launch_bounds__(256) void gather64_l2(
        const int* __restrict__ rowstart, const int* __restrict__ csr,
        const float* __restrict__ dinv,
        const unsigned short* __restrict__ Hs1,   // [M,64] bf16 unscaled
        const float* __restrict__ b1,
        const float* __restrict__ W2,             // [64,16]
        unsigned short* __restrict__ Hs2,         // [M,16] bf16
        int M) {
    __shared__ float Ws2[64 * 16];
    __shared__ float b1s[64];
    __shared__ float srow[8][64];
    for (int i = threadIdx.x; i < 64 * 16; i += 256) Ws2[i] = W2[i];
    if (threadIdx.x < 64) b1s[threadIdx.x] = b1[threadIdx.x];
    __syncthreads();

    const int r = threadIdx.x >> 5;
    const int lf = threadIdx.x & 31;
    const int row = blockIdx.x * 8 + r;
    const bool rok = (row < M);

    float v0 = 0.f, v1 = 0.f;
    if (rok) {
        const unsigned* H32 = (const unsigned*)Hs1;
        int e0 = rowstart[row], e1 = rowstart[row + 1];
        float dd = dinv[row];
        float acc0, acc1;
        bfpair(H32[(size_t)row * 32 + lf], acc0, acc1);
        acc0 *= dd; acc1 *= dd;
        int e = e0;
        for (; e + 3 < e1; e += 4) {
            int s0 = csr[e], s1 = csr[e + 1], s2 = csr[e + 2], s3 = csr[e + 3];
            float w0 = dinv[s0], w1 = dinv[s1], w2 = dinv[s2], w3 = dinv[s3];
            unsigned u0 = H32[(size_t)s0 * 32 + lf];
            unsigned u1 = H32[(size_t)s1 * 32 + lf];
            unsigned u2 = H32[(size_t)s2 * 32 + lf];
            unsigned u3 = H32[(size_t)s3 * 32 + lf];
            float a, b;
            bfpair(u0, a, b); acc0 += w0 * a; acc1 += w0 * b;
            bfpair(u1, a, b); acc0 += w1 * a; acc1 += w1 * b;
            bfpair(u2, a, b); acc0 += w2 * a; acc1 += w2 * b;
            bfpair(u3, a, b); acc0 += w3 * a; acc1 += w3 * b;
        }
        for (; e < e1; e++) {
            int s0 = csr[e];
            float w0 = dinv[s0];
            unsigned u = H32[(size_t)s0 * 32 + lf];
            float a, b;
            bfpair(u, a, b); acc0 += w0 * a; acc1 += w0 * b;
        }
        v0 = fmaxf(acc0 * dd + b1s[2 * lf], 0.f);
        v1 = fmaxf(acc1 * dd + b1s[2 * lf + 1], 0.f);
    }
    float2 t2; t2.x = v0; t2.y = v1;
    *(float2*)&srow[r][2 * lf] = t2;
    __syncthreads();

    if (rok && lf < 16) {
        float acc = 0.f;
#pragma unroll
        for (int k4 = 0; k4 < 16; k4++) {
            float4 s4 = *(const float4*)&srow[r][k4 * 4];
            acc += s4.x * Ws2[(k4 * 4 + 0) * 16 + lf];
            acc += s4.y * Ws2[(k4 * 4 + 1) * 16 + lf];
            acc += s4.z * Ws2[(k4 * 4 + 2) * 16 + lf];
            acc += s4.w * Ws2[(k4 * 4 + 3) * 16 + lf];
        }
        acc *= dinv[row];
        float hi = __shfl_down(acc, 1, 64);
        if ((lf & 1) == 0) {
            unsigned p = (unsigned)f2bf(acc) | ((unsigned)f2bf(hi) << 16);
            ((unsigned*)Hs2)[(size_t)row * 8 + (lf >> 1)] = p;
        }
    }
}

// ---------------- generic CSR gather (layer-2 aggregation; input pre-scaled) ----------------

template <int F, bool RELU, bool SCALEOUT, bool HASBIAS, bool OUTBF>
__global__ __launch_bounds__(256) void gather_bf(
        const int* __restrict__ rowstart,
        const int* __restrict__ csr,
        const float* __restrict__ dinv,
        const unsigned short* __restrict__ Hs,
        const float* __restrict__ bias,
        void* __restrict__ outp,
        int M) {
    constexpr int LANES = F / 2;
    constexpr int GP = 256 / LANES;
    int row = blockIdx.x * GP + threadIdx.x / LANES;
    int lf = threadIdx.x % LANES;
    if (row >= M) return;

    const unsigned* H32 = (const unsigned*)Hs;
    const size_t LP = F / 2;

    int e0 = rowstart[row], e1 = rowstart[row + 1];
    float acc0, acc1;
    bfpair(H32[(size_t)row * LP + lf], acc0, acc1);

    int e = e0;
    for (; e + 3 < e1; e += 4) {
        int s0 = csr[e], s1 = csr[e + 1], s2 = csr[e + 2], s3 = csr[e + 3];
        unsigned u0 = H32[(size_t)s0 * LP + lf];
        unsigned u1 = H32[(size_t)s1 * LP + lf];
        unsigned u2 = H32[(size_t)s2 * LP + lf];
        unsigned u3 = H32[(size_t)s3 * LP + lf];
        float a, b;
        bfpair(u0, a, b); acc0 += a; acc1 += b;
        bfpair(u1, a, b); acc0 += a; acc1 += b;
        bfpair(u2, a, b); acc0 += a; acc1 += b;
        bfpair(u3, a, b); acc0 += a; acc1 += b;
    }
    for (; e < e1; e++) {
        unsigned u = H32[(size_t)csr[e] * LP + lf];
        float a, b;
        bfpair(u, a, b); acc0 += a; acc1 += b;
    }

    float dd = dinv[row];
    float v0 = acc0 * dd, v1 = acc1 * dd;
    if (HASBIAS) { v0 += bias[2 * lf]; v1 += bias[2 * lf + 1]; }
    if (RELU) { v0 = fmaxf(v0, 0.f); v1 = fmaxf(v1, 0.f); }
    if (SCALEOUT) { v0 *= dd; v1 *= dd; }
    if (OUTBF) {
        unsigned p = (unsigned)f2bf(v0) | ((unsigned)f2bf(v1) << 16);
        ((unsigned*)outp)[(size_t)row * LP + lf] = p;
    } else {
        float2 t; t.x = v0; t.y = v1;
        ((float2*)outp)[(size_t)row * LP + lf] = t;
    }
}

// ---------------- layer-3 aggregation + 16->40 matvec + log_softmax ----------------

#define SRP 20

__global__ __launch_bounds__(256) void gather16_final(
        const int* __restrict__ rowstart, const int* __restrict__ csr,
        const float* __restrict__ dinv,
        const unsigned short* __restrict__ r2s,   // [M,16] bf16 pre-scaled
        const float* __restrict__ W3,
        const float* __restrict__ b3,
        float* __restrict__ out,
        int M) {
    __shared__ float Ws3[16 * 40];
    __shared__ float bs3[40];
    __shared__ float srow[32][SRP];
    __shared__ float orow[32 * 40];
    for (int i = threadIdx.x; i < 16 * 40; i += 256) Ws3[i] = W3[i];
    if (threadIdx.x < 40) bs3[threadIdx.x] = b3[threadIdx.x];

    const int r = threadIdx.x >> 3;
    const int lf = threadIdx.x & 7;
    const int row = blockIdx.x * 32 + r;
    const bool rok = (row < M);

    float g0 = 0.f, g1 = 0.f;
    if (rok) {
        const unsigned* H32 = (const unsigned*)r2s;
        int e0 = rowstart[row], e1 = rowstart[row + 1];
        float acc0, acc1;
        bfpair(H32[(size_t)row * 8 + lf], acc0, acc1);
        int e = e0;
        for (; e + 3 < e1; e += 4) {
            int s0 = csr[e], s1 = csr[e + 1], s2 = csr[e + 2], s3 = csr[e + 3];
            unsigned u0 = H32[(size_t)s0 * 8 + lf];
            unsigned u1 = H32[(size_t)s1 * 8 + lf];
            unsigned u2 = H32[(size_t)s2 * 8 + lf];
            unsigned u3 = H32[(size_t)s3 * 8 + lf];
            float a, b;
            bfpair(u0, a, b); acc0 += a; acc1 += b;
            bfpair(u1, a, b); acc0 += a; acc1 += b;
            bfpair(u2, a, b); acc0 += a; acc1 += b;
            bfpair(u3, a, b); acc0 += a; acc1 += b;
        }
        for (; e < e1; e++) {
            unsigned u = H32[(size_t)csr[e] * 8 + lf];
            float a, b;
            bfpair(u, a, b); acc0 += a; acc1 += b;
        }
        float dd = dinv[row];
        g0 = acc0 * dd; g1 = acc1 * dd;
    }
    float2 t2; t2.x = g0; t2.y = g1;
    *(float2*)&srow[r][2 * lf] = t2;
    __syncthreads();

    float vals[5];
#pragma unroll
    for (int q = 0; q < 5; q++) vals[q] = bs3[lf + 8 * q];
#pragma unroll
    for (int k4 = 0; k4 < 4; k4++) {
        float4 s4 = *(const float4*)&srow[r][k4 * 4];
#pragma unroll
        for (int q = 0; q < 5; q++) {
            int n = lf + 8 * q;
            vals[q] += s4.x * Ws3[(k4 * 4 + 0) * 40 + n];
            vals[q] += s4.y * Ws3[(k4 * 4 + 1) * 40 + n];
            vals[q] += s4.z * Ws3[(k4 * 4 + 2) * 40 + n];
            vals[q] += s4.w * Ws3[(k4 * 4 + 3) * 40 + n];
        }
    }
    float m = vals[0];
#pragma unroll
    for (int q = 1; q < 5; q++) m = fmaxf(m, vals[q]);
#pragma unroll
    for (int off = 1; off < 8; off <<= 1) m = fmaxf(m, __shfl_xor(m, off, 64));
    float s = 0.f;
#pragma unroll
    for (int q = 0; q < 5; q++) s += expf(vals[q] - m);
#pragma unroll
    for (int off = 1; off < 8; off <<= 1) s += __shfl_xor(s, off, 64);
    float ls = logf(s) + m;
#pragma unroll
    for (int q = 0; q < 5; q++) orow[r * 40 + lf + 8 * q] = vals[q] - ls;
    __syncthreads();

    float4* o4 = (float4*)(out + (size_t)blockIdx.x * 32 * 40);
    const float4* s4p = (const float4*)orow;
    for (int i = threadIdx.x; i < 320; i += 256) {
        int rr = (i * 4) / 40;
        if (blockIdx.x * 32 + rr < M) o4[i] = s4p[i];
    }
}

// ---------------- launch ----------------

extern "C" void kernel_launch(void* const* d_in, const int* in_sizes, int n_in,
                              void* d_out, int out_size, void* d_ws, size_t ws_size,
                              hipStream_t stream) {
    const float* x   = (const float*)d_in[0];
    const int*   ei  = (const int*)d_in[1];
    const int*   src = ei;
    const int*   dst = ei + NEDGES;
    const float* W1 = (const float*)d_in[2];
    const float* b1 = (const float*)d_in[3];
    const float* W2 = (const float*)d_in[4];
    const float* b2 = (const float*)d_in[5];
    const float* W3 = (const float*)d_in[6];
    const float* b3 = (const float*)d_in[7];
    float* out = (float*)d_out;

    int* ws_i = (int*)d_ws;
    int* wcur     = ws_i;                        // NWIN*WSTR
    int* rowstart = wcur + NWIN * WSTR + 16;     // N+8
    int* csr      = rowstart + NNODES + 8;       // E
    unsigned* stage = (unsigned*)(csr + NEDGES); // NWIN*WCAP
    float* dinv   = (float*)(stage + (size_t)NWIN * WCAP);  // N
    unsigned short* Wt = (unsigned short*)(dinv + NNODES);  // 64*512 bf16
    float* bufA   = (float*)((int*)(Wt + 64 * 512) + 16);
    float* bufB   = bufA + (size_t)NNODES * 64;

    unsigned short* Hs1 = (unsigned short*)bufA;   // [N,64] bf16 unscaled
    unsigned short* Hs2 = (unsigned short*)bufB;   // [N,16] bf16
    unsigned short* r2s = (unsigned short*)bufA;   // [N,16] bf16 (Hs1 dead)

    // --- W1 -> bf16^T + wcur zero ---
    convW<<<128, 256, 0, stream>>>(W1, Wt, wcur);

    // --- MEGA: DMA-staged GEMM (x@W1, unscaled) overlapped with edge bucketing ---
    mega_gemm_bucket<<<MEGA_BLOCKS, 256, 0, stream>>>(
        x, Wt, Hs1, src, dst, stage, wcur, NNODES, NEDGES);

    // --- CSR finalize: one block per window ---
    csr_window<<<NWIN, 256, 0, stream>>>(stage, wcur, rowstart, dinv, csr);

    // --- layer-1 aggregation (per-edge dinv) + fused 64->16 transform ---
    gather64_l2<<<(NNODES + 7) / 8, 256, 0, stream>>>(
        rowstart, csr, dinv, Hs1, b1, W2, Hs2, NNODES);

    // --- layer-2 aggregation (relu + b2 + pre-scale) ---
    gather_bf<16, true, true, true, true><<<(NNODES + 31) / 32, 256, 0, stream>>>(
        rowstart, csr, dinv, Hs2, b2, r2s, NNODES);

    // --- layer-3 aggregation + 16->40 matvec + log_softmax ---
    gather16_final<<<(NNODES + 31) / 32, 256, 0, stream>>>(
        rowstart, csr, dinv, r2s, W3, b3, out, NNODES);
}

// Round 17
// 210.143 us; speedup vs baseline: 1.0779x; 1.0779x over previous
//
#include <hip/hip_runtime.h>
#include <cstdint>
#include <cstddef>

#define NNODES 100000
#define NEDGES 1600000
#define NWIN 100
#define WIN_NODES 1000
#define WCAP 17408
#define WSTR 16

#define GM_ROWS 16
#define GEMM_BLOCKS (NNODES / GM_ROWS)                   // 6250 (exact)
#define BUCKET_BLOCKS 512
#define BCHUNK ((NEDGES + BUCKET_BLOCKS - 1) / BUCKET_BLOCKS)  // 3125
#define MEGA_BLOCKS (GEMM_BLOCKS + BUCKET_BLOCKS)        // 6762

typedef __attribute__((ext_vector_type(8))) short bf16x8;
typedef __attribute__((ext_vector_type(4))) float f32x4;

__device__ inline unsigned short f2bf(float f) {
    union { float f; unsigned u; } v; v.f = f;
    unsigned r = v.u + 0x7FFFu + ((v.u >> 16) & 1u);   // RNE
    return (unsigned short)(r >> 16);
}
__device__ inline void bfpair(unsigned u, float& lo, float& hi) {
    union { unsigned x; float f; } a, b;
    a.x = u << 16; b.x = u & 0xffff0000u;
    lo = a.f; hi = b.f;
}

#define GLOAD_LDS16(gp, lp)                                                        \
    __builtin_amdgcn_global_load_lds(                                              \
        (__attribute__((address_space(1))) const void*)(gp),                       \
        (__attribute__((address_space(3))) void*)(lp), 16, 0, 0)

// ---------------- convW v2: W1 -> Wfrag (lane-coalesced MFMA B-fragments) ----------------
// Wfrag[frag][lane][j]: frag = (t*2+kf)*4+cf; value = bf16(W1[k][n]),
// k = t*64 + kf*32 + (lane>>4)*8 + j, n = cf*16 + (lane&15).
// A wave loading frag at (base + lane*16B) gets its MFMA B-operand directly.

__global__ __launch_bounds__(256) void convW(const float* __restrict__ W,
                                             unsigned short* __restrict__ Wfrag,
                                             int* __restrict__ wcur) {
    if (blockIdx.x == 0 && threadIdx.x < NWIN) wcur[threadIdx.x * WSTR] = 0;
    int tid = blockIdx.x * 256 + threadIdx.x;     // one 16B slot per thread
    if (tid < 64 * 64) {
        int frag = tid >> 6, lane = tid & 63;
        int cf = frag & 3, kf = (frag >> 2) & 1, t = frag >> 3;
        int n = cf * 16 + (lane & 15);
        int kb = t * 64 + kf * 32 + (lane >> 4) * 8;
#pragma unroll
        for (int j = 0; j < 8; j++)
            Wfrag[(size_t)frag * 512 + lane * 8 + j] = f2bf(W[(size_t)(kb + j) * 64 + n]);
    }
}

// ---------------- MEGA kernel: pipelined GEMM role + edge-bucketing role ----------------
// GEMM role: B in 64 persistent VGPRs/lane (Wfrag, loaded once) -> A-DMA is the
// ONLY VMEM stream in the k-loop. Wave 0 produces A via global_load_lds, 4-slot
// rotation, TRUE 2-deep (counted vmcnt(8), never 0 mid-loop), raw s_barrier
// (no drain). Source-side XOR swizzle (m173) keeps ds_reads conflict-light.

__global__ __launch_bounds__(256) void mega_gemm_bucket(
        const float* __restrict__ A,              // [M,512] x
        const unsigned short* __restrict__ Wfrag, // 64KB B fragments
        unsigned short* __restrict__ Hs,          // [M,64] bf16 UNSCALED out
        const int* __restrict__ src, const int* __restrict__ dst,
        unsigned* __restrict__ stage,
        int* __restrict__ wcur, int M, int E) {
    __shared__ __align__(16) char smem[16384];    // 4 slots x 16 rows x 64 f32

    long long b = blockIdx.x;
    int g0 = (int)((b * GEMM_BLOCKS) / MEGA_BLOCKS);
    int g1 = (int)(((b + 1) * GEMM_BLOCKS) / MEGA_BLOCKS);

    if (g1 > g0) {
        // ---------------- GEMM role ----------------
        const int tid = threadIdx.x;
        const int wv = tid >> 6;                  // wave's cf quarter
        const int lane = tid & 63;
        const int lm = lane & 15;
        const int lk8 = lane >> 4;
        const int bm = g0 * GM_ROWS;

        // B: 16 coalesced 16B loads -> 64 persistent VGPRs (this wave's cf = wv)
        bf16x8 Breg[8][2];
#pragma unroll
        for (int t = 0; t < 8; t++)
#pragma unroll
            for (int kf = 0; kf < 2; kf++)
                Breg[t][kf] = *(const bf16x8*)&Wfrag[(size_t)(((t * 2 + kf) * 4 + wv) * 64
                                                              + lane) * 8];

        f32x4 acc = (f32x4){0.f, 0.f, 0.f, 0.f};

        auto ISSUE = [&](int t) {                 // wave 0 only
            int slot = t & 3;
#pragma unroll
            for (int i = 0; i < 4; i++) {
                int rl = 4 * i + lk8;
                int su = lm ^ rl;                 // pre-swizzled 16B unit
                const float* gp = A + (size_t)(bm + rl) * 512 + t * 64 + su * 4;
                char* lp = smem + slot * 4096 + i * 1024;
                GLOAD_LDS16(gp, lp);
            }
        };

        if (wv == 0) { ISSUE(0); ISSUE(1); }

#pragma unroll
        for (int t = 0; t < 8; t++) {
            if (wv == 0) {
                if (t + 2 < 8) ISSUE(t + 2);
                if (t <= 5)      { asm volatile("s_waitcnt vmcnt(8)" ::: "memory"); }
                else if (t == 6) { asm volatile("s_waitcnt vmcnt(4)" ::: "memory"); }
                else             { asm volatile("s_waitcnt vmcnt(0)" ::: "memory"); }
                __builtin_amdgcn_sched_barrier(0);
            }
            __builtin_amdgcn_s_barrier();         // raw: no vmcnt drain

            const char* base = smem + (t & 3) * 4096 + lm * 256;
            bf16x8 af[2];
#pragma unroll
            for (int kf = 0; kf < 2; kf++) {
                int u0 = kf * 8 + (lk8 << 1);
                float4 lo = *(const float4*)(base + (((u0)     ^ lm) << 4));
                float4 hi = *(const float4*)(base + (((u0 + 1) ^ lm) << 4));
                unsigned c[4];
                asm("v_cvt_pk_bf16_f32 %0, %1, %2" : "=v"(c[0]) : "v"(lo.x), "v"(lo.y));
                asm("v_cvt_pk_bf16_f32 %0, %1, %2" : "=v"(c[1]) : "v"(lo.z), "v"(lo.w));
                asm("v_cvt_pk_bf16_f32 %0, %1, %2" : "=v"(c[2]) : "v"(hi.x), "v"(hi.y));
                asm("v_cvt_pk_bf16_f32 %0, %1, %2" : "=v"(c[3]) : "v"(hi.z), "v"(hi.w));
                af[kf] = *(bf16x8*)c;
            }

            __builtin_amdgcn_s_setprio(1);
#pragma unroll
            for (int kf = 0; kf < 2; kf++)
                acc = __builtin_amdgcn_mfma_f32_16x16x32_bf16(af[kf], Breg[t][kf], acc, 0, 0, 0);
            __builtin_amdgcn_s_setprio(0);
        }

        // epilogue: D col = lane&15 (within wave's 16-col quarter), row = (lane>>4)*4+j
#pragma unroll
        for (int j = 0; j < 4; j++) {
            int row = bm + (lane >> 4) * 4 + j;
            Hs[(size_t)row * 64 + wv * 16 + lm] = f2bf(acc[j]);
        }
    } else {
        // ---------------- bucket role ----------------
        int bi = (int)(b - g0);
        int* cnt  = (int*)smem;
        int* lcur = cnt + NWIN;
        const int tid = threadIdx.x;
        int e0 = bi * BCHUNK;
        int e1 = e0 + BCHUNK; if (e1 > E) e1 = E;

        for (int i = tid; i < NWIN; i += 256) cnt[i] = 0;
        __syncthreads();
        for (int e = e0 + tid; e < e1; e += 256)
            atomicAdd(&cnt[dst[e] / WIN_NODES], 1);
        __syncthreads();
        for (int i = tid; i < NWIN; i += 256)
            lcur[i] = atomicAdd(&wcur[i * WSTR], cnt[i]);
        __syncthreads();
        for (int e = e0 + tid; e < e1; e += 256) {
            int d = dst[e], s = src[e];
            int w = d / WIN_NODES;
            int pos = atomicAdd(&lcur[w], 1);
            if (pos < WCAP)
                stage[(size_t)w * WCAP + pos] =
                    ((unsigned)(d - w * WIN_NODES) << 17) | (unsigned)s;
        }
    }
}

// ---------------- csr_window: hist + scan + dinv + rowstart + fill ----------------

__global__ __launch_bounds__(256) void csr_window(
        const unsigned* __restrict__ stage,
        const int* __restrict__ wcur,
        int* __restrict__ rowstart,   // [NNODES+1]
        float* __restrict__ dinv,     // [NNODES]
        int* __restrict__ csr) {
    __shared__ int cnt[WIN_NODES];
    __shared__ int red[256];
    const int w = blockIdx.x;
    const int t = threadIdx.x;
    const int wb = w * WIN_NODES;
    const size_t sb = (size_t)w * WCAP;

    int v = (t < w) ? min(wcur[t * WSTR], WCAP) : 0;
    red[t] = v;
    __syncthreads();
#pragma unroll
    for (int off = 128; off > 0; off >>= 1) {
        if (t < off) red[t] += red[t + off];
        __syncthreads();
    }
    int woff = red[0];
    int n_w = min(wcur[w * WSTR], WCAP);
    __syncthreads();

    for (int i = t; i < WIN_NODES; i += 256) cnt[i] = 0;
    __syncthreads();
    for (int i = t; i < n_w; i += 256)
        atomicAdd(&cnt[stage[sb + i] >> 17], 1);
    __syncthreads();

    int c0 = 0, c1 = 0, c2 = 0, c3 = 0, psum = 0;
    if (t < 250) {
        c0 = cnt[4 * t]; c1 = cnt[4 * t + 1]; c2 = cnt[4 * t + 2]; c3 = cnt[4 * t + 3];
        psum = c0 + c1 + c2 + c3;
    }
    red[t] = psum;
    __syncthreads();
#pragma unroll
    for (int off = 1; off < 256; off <<= 1) {
        int tv = (t >= off) ? red[t - off] : 0;
        __syncthreads();
        red[t] += tv;
        __syncthreads();
    }
    int excl = red[t] - psum;
    if (t < 250) {
        int running = woff + excl;
        int idx = 4 * t;
        rowstart[wb + idx] = running; dinv[wb + idx] = rsqrtf((float)c0 + 1.f);
        cnt[idx] = running; running += c0;
        rowstart[wb + idx + 1] = running; dinv[wb + idx + 1] = rsqrtf((float)c1 + 1.f);
        cnt[idx + 1] = running; running += c1;
        rowstart[wb + idx + 2] = running; dinv[wb + idx + 2] = rsqrtf((float)c2 + 1.f);
        cnt[idx + 2] = running; running += c2;
        rowstart[wb + idx + 3] = running; dinv[wb + idx + 3] = rsqrtf((float)c3 + 1.f);
        cnt[idx + 3] = running;
    }
    if (w == NWIN - 1 && t == 0) rowstart[NNODES] = woff + n_w;
    __syncthreads();

    for (int i = t; i < n_w; i += 256) {
        unsigned p = stage[sb + i];
        int dl = (int)(p >> 17);
        int s  = (int)(p & 0x1FFFFu);
        int pos = atomicAdd(&cnt[dl], 1);
        csr[pos] = s;
    }
}

// ---------------- gather64 + fused 64->16 transform (per-edge dinv) ----------------

__global__ __launch_bounds__(256) void gather64_l2(
        const int* __restrict__ rowstart, const int* __restrict__ csr,
        const float* __restrict__ dinv,
        const unsigned short* __restrict__ Hs1,   // [M,64] bf16 unscaled
        const float* __restrict__ b1,
        const float* __restrict__ W2,             // [64,16]
        unsigned short* __restrict__ Hs2,         // [M,16] bf16
        int M) {
    __shared__ float Ws2[64 * 16];
    __shared__ float b1s[64];
    __shared__ float srow[8][64];
    for (int i = threadIdx.x; i < 64 * 16; i += 256) Ws2[i] = W2[i];
    if (threadIdx.x < 64) b1s[threadIdx.x] = b1[threadIdx.x];
    __syncthreads();

    const int r = threadIdx.x >> 5;
    const int lf = threadIdx.x & 31;
    const int row = blockIdx.x * 8 + r;
    const bool rok = (row < M);

    float v0 = 0.f, v1 = 0.f;
    if (rok) {
        const unsigned* H32 = (const unsigned*)Hs1;
        int e0 = rowstart[row], e1 = rowstart[row + 1];
        float dd = dinv[row];
        float acc0, acc1;
        bfpair(H32[(size_t)row * 32 + lf], acc0, acc1);
        acc0 *= dd; acc1 *= dd;
        int e = e0;
        for (; e + 3 < e1; e += 4) {
            int s0 = csr[e], s1 = csr[e + 1], s2 = csr[e + 2], s3 = csr[e + 3];
            float w0 = dinv[s0], w1 = dinv[s1], w2 = dinv[s2], w3 = dinv[s3];
            unsigned u0 = H32[(size_t)s0 * 32 + lf];
            unsigned u1 = H32[(size_t)s1 * 32 + lf];
            unsigned u2 = H32[(size_t)s2 * 32 + lf];
            unsigned u3 = H32[(size_t)s3 * 32 + lf];
            float a, b;
            bfpair(u0, a, b); acc0 += w0 * a; acc1 += w0 * b;
            bfpair(u1, a, b); acc0 += w1 * a; acc1 += w1 * b;
            bfpair(u2, a, b); acc0 += w2 * a; acc1 += w2 * b;
            bfpair(u3, a, b); acc0 += w3 * a; acc1 += w3 * b;
        }
        for (; e < e1; e++) {
            int s0 = csr[e];
            float w0 = dinv[s0];
            unsigned u = H32[(size_t)s0 * 32 + lf];
            float a, b;
            bfpair(u, a, b); acc0 += w0 * a; acc1 += w0 * b;
        }
        v0 = fmaxf(acc0 * dd + b1s[2 * lf], 0.f);
        v1 = fmaxf(acc1 * dd + b1s[2 * lf + 1], 0.f);
    }
    float2 t2; t2.x = v0; t2.y = v1;
    *(float2*)&srow[r][2 * lf] = t2;
    __syncthreads();

    if (rok && lf < 16) {
        float acc = 0.f;
#pragma unroll
        for (int k4 = 0; k4 < 16; k4++) {
            float4 s4 = *(const float4*)&srow[r][k4 * 4];
            acc += s4.x * Ws2[(k4 * 4 + 0) * 16 + lf];
            acc += s4.y * Ws2[(k4 * 4 + 1) * 16 + lf];
            acc += s4.z * Ws2[(k4 * 4 + 2) * 16 + lf];
            acc += s4.w * Ws2[(k4 * 4 + 3) * 16 + lf];
        }
        acc *= dinv[row];
        float hi = __shfl_down(acc, 1, 64);
        if ((lf & 1) == 0) {
            unsigned p = (unsigned)f2bf(acc) | ((unsigned)f2bf(hi) << 16);
            ((unsigned*)Hs2)[(size_t)row * 8 + (lf >> 1)] = p;
        }
    }
}

// ---------------- generic CSR gather (layer-2 aggregation; input pre-scaled) ----------------

template <int F, bool RELU, bool SCALEOUT, bool HASBIAS, bool OUTBF>
__global__ __launch_bounds__(256) void gather_bf(
        const int* __restrict__ rowstart,
        const int* __restrict__ csr,
        const float* __restrict__ dinv,
        const unsigned short* __restrict__ Hs,
        const float* __restrict__ bias,
        void* __restrict__ outp,
        int M) {
    constexpr int LANES = F / 2;
    constexpr int GP = 256 / LANES;
    int row = blockIdx.x * GP + threadIdx.x / LANES;
    int lf = threadIdx.x % LANES;
    if (row >= M) return;

    const unsigned* H32 = (const unsigned*)Hs;
    const size_t LP = F / 2;

    int e0 = rowstart[row], e1 = rowstart[row + 1];
    float acc0, acc1;
    bfpair(H32[(size_t)row * LP + lf], acc0, acc1);

    int e = e0;
    for (; e + 3 < e1; e += 4) {
        int s0 = csr[e], s1 = csr[e + 1], s2 = csr[e + 2], s3 = csr[e + 3];
        unsigned u0 = H32[(size_t)s0 * LP + lf];
        unsigned u1 = H32[(size_t)s1 * LP + lf];
        unsigned u2 = H32[(size_t)s2 * LP + lf];
        unsigned u3 = H32[(size_t)s3 * LP + lf];
        float a, b;
        bfpair(u0, a, b); acc0 += a; acc1 += b;
        bfpair(u1, a, b); acc0 += a; acc1 += b;
        bfpair(u2, a, b); acc0 += a; acc1 += b;
        bfpair(u3, a, b); acc0 += a; acc1 += b;
    }
    for (; e < e1; e++) {
        unsigned u = H32[(size_t)csr[e] * LP + lf];
        float a, b;
        bfpair(u, a, b); acc0 += a; acc1 += b;
    }

    float dd = dinv[row];
    float v0 = acc0 * dd, v1 = acc1 * dd;
    if (HASBIAS) { v0 += bias[2 * lf]; v1 += bias[2 * lf + 1]; }
    if (RELU) { v0 = fmaxf(v0, 0.f); v1 = fmaxf(v1, 0.f); }
    if (SCALEOUT) { v0 *= dd; v1 *= dd; }
    if (OUTBF) {
        unsigned p = (unsigned)f2bf(v0) | ((unsigned)f2bf(v1) << 16);
        ((unsigned*)outp)[(size_t)row * LP + lf] = p;
    } else {
        float2 t; t.x = v0; t.y = v1;
        ((float2*)outp)[(size_t)row * LP + lf] = t;
    }
}

// ---------------- layer-3 aggregation + 16->40 matvec + log_softmax ----------------

#define SRP 20

__global__ __launch_bounds__(256) void gather16_final(
        const int* __restrict__ rowstart, const int* __restrict__ csr,
        const float* __restrict__ dinv,
        const unsigned short* __restrict__ r2s,   // [M,16] bf16 pre-scaled
        const float* __restrict__ W3,
        const float* __restrict__ b3,
        float* __restrict__ out,
        int M) {
    __shared__ float Ws3[16 * 40];
    __shared__ float bs3[40];
    __shared__ float srow[32][SRP];
    __shared__ float orow[32 * 40];
    for (int i = threadIdx.x; i < 16 * 40; i += 256) Ws3[i] = W3[i];
    if (threadIdx.x < 40) bs3[threadIdx.x] = b3[threadIdx.x];

    const int r = threadIdx.x >> 3;
    const int lf = threadIdx.x & 7;
    const int row = blockIdx.x * 32 + r;
    const bool rok = (row < M);

    float g0 = 0.f, g1 = 0.f;
    if (rok) {
        const unsigned* H32 = (const unsigned*)r2s;
        int e0 = rowstart[row], e1 = rowstart[row + 1];
        float acc0, acc1;
        bfpair(H32[(size_t)row * 8 + lf], acc0, acc1);
        int e = e0;
        for (; e + 3 < e1; e += 4) {
            int s0 = csr[e], s1 = csr[e + 1], s2 = csr[e + 2], s3 = csr[e + 3];
            unsigned u0 = H32[(size_t)s0 * 8 + lf];
            unsigned u1 = H32[(size_t)s1 * 8 + lf];
            unsigned u2 = H32[(size_t)s2 * 8 + lf];
            unsigned u3 = H32[(size_t)s3 * 8 + lf];
            float a, b;
            bfpair(u0, a, b); acc0 += a; acc1 += b;
            bfpair(u1, a, b); acc0 += a; acc1 += b;
            bfpair(u2, a, b); acc0 += a; acc1 += b;
            bfpair(u3, a, b); acc0 += a; acc1 += b;
        }
        for (; e < e1; e++) {
            unsigned u = H32[(size_t)csr[e] * 8 + lf];
            float a, b;
            bfpair(u, a, b); acc0 += a; acc1 += b;
        }
        float dd = dinv[row];
        g0 = acc0 * dd; g1 = acc1 * dd;
    }
    float2 t2; t2.x = g0; t2.y = g1;
    *(float2*)&srow[r][2 * lf] = t2;
    __syncthreads();

    float vals[5];
#pragma unroll
    for (int q = 0; q < 5; q++) vals[q] = bs3[lf + 8 * q];
#pragma unroll
    for (int k4 = 0; k4 < 4; k4++) {
        float4 s4 = *(const float4*)&srow[r][k4 * 4];
#pragma unroll
        for (int q = 0; q < 5; q++) {
            int n = lf + 8 * q;
            vals[q] += s4.x * Ws3[(k4 * 4 + 0) * 40 + n];
            vals[q] += s4.y * Ws3[(k4 * 4 + 1) * 40 + n];
            vals[q] += s4.z * Ws3[(k4 * 4 + 2) * 40 + n];
            vals[q] += s4.w * Ws3[(k4 * 4 + 3) * 40 + n];
        }
    }
    float m = vals[0];
#pragma unroll
    for (int q = 1; q < 5; q++) m = fmaxf(m, vals[q]);
#pragma unroll
    for (int off = 1; off < 8; off <<= 1) m = fmaxf(m, __shfl_xor(m, off, 64));
    float s = 0.f;
#pragma unroll
    for (int q = 0; q < 5; q++) s += expf(vals[q] - m);
#pragma unroll
    for (int off = 1; off < 8; off <<= 1) s += __shfl_xor(s, off, 64);
    float ls = logf(s) + m;
#pragma unroll
    for (int q = 0; q < 5; q++) orow[r * 40 + lf + 8 * q] = vals[q] - ls;
    __syncthreads();

    float4* o4 = (float4*)(out + (size_t)blockIdx.x * 32 * 40);
    const float4* s4p = (const float4*)orow;
    for (int i = threadIdx.x; i < 320; i += 256) {
        int rr = (i * 4) / 40;
        if (blockIdx.x * 32 + rr < M) o4[i] = s4p[i];
    }
}

// ---------------- launch ----------------

extern "C" void kernel_launch(void* const* d_in, const int* in_sizes, int n_in,
                              void* d_out, int out_size, void* d_ws, size_t ws_size,
                              hipStream_t stream) {
    const float* x   = (const float*)d_in[0];
    const int*   ei  = (const int*)d_in[1];
    const int*   src = ei;
    const int*   dst = ei + NEDGES;
    const float* W1 = (const float*)d_in[2];
    const float* b1 = (const float*)d_in[3];
    const float* W2 = (const float*)d_in[4];
    const float* b2 = (const float*)d_in[5];
    const float* W3 = (const float*)d_in[6];
    const float* b3 = (const float*)d_in[7];
    float* out = (float*)d_out;

    int* ws_i = (int*)d_ws;
    int* wcur     = ws_i;                        // NWIN*WSTR
    int* rowstart = wcur + NWIN * WSTR + 16;     // N+8
    int* csr      = rowstart + NNODES + 8;       // E
    unsigned* stage = (unsigned*)(csr + NEDGES); // NWIN*WCAP
    float* dinv   = (float*)(stage + (size_t)NWIN * WCAP);  // N
    unsigned short* Wfrag = (unsigned short*)(dinv + NNODES);  // 64KB
    float* bufA   = (float*)((int*)(Wfrag + 64 * 512) + 16);
    float* bufB   = bufA + (size_t)NNODES * 64;

    unsigned short* Hs1 = (unsigned short*)bufA;   // [N,64] bf16 unscaled
    unsigned short* Hs2 = (unsigned short*)bufB;   // [N,16] bf16
    unsigned short* r2s = (unsigned short*)bufA;   // [N,16] bf16 (Hs1 dead)

    // --- W1 -> fragment layout + wcur zero ---
    convW<<<16, 256, 0, stream>>>(W1, Wfrag, wcur);

    // --- MEGA: pipelined GEMM (x@W1, unscaled) overlapped with edge bucketing ---
    mega_gemm_bucket<<<MEGA_BLOCKS, 256, 0, stream>>>(
        x, Wfrag, Hs1, src, dst, stage, wcur, NNODES, NEDGES);

    // --- CSR finalize: one block per window ---
    csr_window<<<NWIN, 256, 0, stream>>>(stage, wcur, rowstart, dinv, csr);

    // --- layer-1 aggregation (per-edge dinv) + fused 64->16 transform ---
    gather64_l2<<<(NNODES + 7) / 8, 256, 0, stream>>>(
        rowstart, csr, dinv, Hs1, b1, W2, Hs2, NNODES);

    // --- layer-2 aggregation (relu + b2 + pre-scale) ---
    gather_bf<16, true, true, true, true><<<(NNODES + 31) / 32, 256, 0, stream>>>(
        rowstart, csr, dinv, Hs2, b2, r2s, NNODES);

    // --- layer-3 aggregation + 16->40 matvec + log_softmax ---
    gather16_final<<<(NNODES + 31) / 32, 256, 0, stream>>>(
        rowstart, csr, dinv, r2s, W3, b3, out, NNODES);
}